// Round 6
// baseline (773.042 us; speedup 1.0000x reference)
//
#include <hip/hip_runtime.h>
#include <hip/hip_bf16.h>

#define BATCH 16
#define NH    8
#define CH    8
#define HH    56
#define WW    56
#define POS   3136          // 56*56 = 49*64
#define QKVC  192
#define OC    64
#define SCALE 0.17677669529663687f   // 32^-0.5

typedef __attribute__((ext_vector_type(8))) short bf16x8;   // 8 bf16 = 4 VGPRs
typedef __attribute__((ext_vector_type(4))) float f32x4;

__device__ __forceinline__ unsigned short f2b(float f) {
    __hip_bfloat16 h = __float2bfloat16(f);
    union { __hip_bfloat16 h; unsigned short u; } c; c.h = h; return c.u;
}
__device__ __forceinline__ unsigned int pk(float lo, float hi) {
    return (unsigned int)f2b(lo) | ((unsigned int)f2b(hi) << 16);
}

// ---------------------------------------------------------------------------
// Kernel A: qkv = x @ qkv_w^T + qkv_b via bf16 MFMA, f[b][o][pos] fp32.
// Mtile=64, Ntile=96, FULL K=256 staged once -> 48 MFMAs/wave, no inner
// barriers. LDS 84.5 KB (1 block/CU; 6.1 blocks/CU sequential).
// grid (49, 2, 16), 256 thr.
// ---------------------------------------------------------------------------
__global__ __launch_bounds__(256) void qkv_mfma(const float* __restrict__ x,
                                                const float* __restrict__ w,
                                                const float* __restrict__ bias,
                                                float* __restrict__ f) {
    __shared__ __align__(16) unsigned short wa[64 * 264];   // [m=pos][k=c] stride 264
    __shared__ __align__(16) unsigned short wb[96 * 264];   // [n=o][k=c]
    const int tid = threadIdx.x;
    const int p0  = blockIdx.x * 64;
    const int o0  = blockIdx.y * 96;
    const int b   = blockIdx.z;

    // stage A: transpose x[c][p0..p0+63] fp32 -> wa[p][c] bf16, all 256 c.
    // wave reads 32 c-rows x 64B pos-chunks = full lines.
    {
        const float* xb = x + (size_t)b * 256 * POS + p0;
        const int cl = (tid & 15) * 2;       // c-pair base
        const int p4 = (tid >> 4) * 4;       // 4 pos per thread
        #pragma unroll
        for (int it = 0; it < 8; ++it) {
            const int c2 = cl + it * 32;
            const float4 r0 = *(const float4*)(xb + (size_t)c2 * POS + p4);
            const float4 r1 = *(const float4*)(xb + (size_t)(c2 + 1) * POS + p4);
            *(unsigned int*)&wa[(p4 + 0) * 264 + c2] = pk(r0.x, r1.x);
            *(unsigned int*)&wa[(p4 + 1) * 264 + c2] = pk(r0.y, r1.y);
            *(unsigned int*)&wa[(p4 + 2) * 264 + c2] = pk(r0.z, r1.z);
            *(unsigned int*)&wa[(p4 + 3) * 264 + c2] = pk(r0.w, r1.w);
        }
    }
    // stage B: w[o0+o][c] 96x256 fp32 -> bf16
    for (int idx = tid; idx < 96 * 64; idx += 256) {
        int o  = idx >> 6;
        int c4 = (idx & 63) << 2;
        const float4 t = *(const float4*)(w + (size_t)(o0 + o) * 256 + c4);
        *(unsigned int*)&wb[o * 264 + c4]     = pk(t.x, t.y);
        *(unsigned int*)&wb[o * 264 + c4 + 2] = pk(t.z, t.w);
    }
    __syncthreads();

    const int lane = tid & 63;
    const int wid  = tid >> 6;          // wave 0..3
    const int m0   = wid * 16;
    const int ml   = lane & 15;
    const int kg   = lane >> 4;         // 0..3

    f32x4 acc[6];
    #pragma unroll
    for (int u = 0; u < 6; ++u) acc[u] = (f32x4){0.f, 0.f, 0.f, 0.f};

    #pragma unroll
    for (int ks = 0; ks < 8; ++ks) {
        const int c0 = ks * 32;
        bf16x8 af = *(const bf16x8*)&wa[(m0 + ml) * 264 + c0 + kg * 8];
        #pragma unroll
        for (int u = 0; u < 6; ++u) {
            bf16x8 bf = *(const bf16x8*)&wb[(u * 16 + ml) * 264 + c0 + kg * 8];
            acc[u] = __builtin_amdgcn_mfma_f32_16x16x32_bf16(af, bf, acc[u], 0, 0, 0);
        }
    }

    // epilogue: D row=(kg*4+r)=pos offset, col=ml=o offset
    #pragma unroll
    for (int u = 0; u < 6; ++u) {
        int o = o0 + u * 16 + ml;
        float bj = bias[o];
        float4 st = { acc[u][0] + bj, acc[u][1] + bj, acc[u][2] + bj, acc[u][3] + bj };
        *(float4*)(f + ((size_t)b * QKVC + o) * POS + p0 + m0 + kg * 4) = st;
    }
}

// ---------------------------------------------------------------------------
// Kernel B: slide attention (fp32). V streamed through the same LDS plane
// buffer as K (LDS 22 KB) + VGPR cap for 3 resident blocks/CU.
// grid (7, 8, 16), 448 thr.
// ---------------------------------------------------------------------------
#define TBH 8
__global__ __launch_bounds__(448, 6) void attn_kernel(const float* __restrict__ f,
                                                      const float* __restrict__ dc_b,
                                                      const float* __restrict__ dc1_w,
                                                      const float* __restrict__ dc1_b,
                                                      const float* __restrict__ rpb,
                                                      float* __restrict__ aout) {
    __shared__ float sbuf[CH][TBH + 2][WW + 2];   // k halo, then v halo
    __shared__ float wcp[CH * 9 * 12];

    const int tid = threadIdx.x;
    const int ty0 = blockIdx.x * TBH;
    const int h   = blockIdx.y;
    const int b   = blockIdx.z;
    const float* fb = f + ((size_t)b * QKVC + h * 24) * POS;

    const int HALO = (TBH + 2) * (WW + 2);   // 580

    // ---- load k halo (8 planes) + weights
    for (int idx = tid; idx < 8 * HALO; idx += 448) {
        int ch  = idx / HALO;
        int rem = idx - ch * HALO;
        int row = rem / (WW + 2);
        int col = rem - row * (WW + 2);
        int gy = ty0 + row - 1;
        int gx = col - 1;
        float val = 0.f;
        if (gy >= 0 && gy < HH && gx >= 0 && gx < WW)
            val = fb[(8 + ch) * POS + gy * WW + gx];
        (&sbuf[0][0][0])[idx] = val;
    }
    for (int idx = tid; idx < 72; idx += 448) {
        int base = idx * 12;
        #pragma unroll
        for (int j = 0; j < 9; ++j) wcp[base + j] = dc1_w[idx * 9 + j];
        float db = dc_b[idx] + dc1_b[idx];
        int ka = idx % 9;
        wcp[base + 9]  = db + rpb[h * 9 + ka];
        wcp[base + 10] = db;
        wcp[base + 11] = 0.f;
    }
    __syncthreads();

    const int ly  = tid / WW;
    const int lx  = tid - ly * WW;
    const int pos = (ty0 + ly) * WW + lx;

    float q[CH];
    #pragma unroll
    for (int ch = 0; ch < CH; ++ch) q[ch] = fb[ch * POS + pos] * SCALE;

    // ---- K pass: logits
    float logits[9];
    #pragma unroll
    for (int ka = 0; ka < 9; ++ka) logits[ka] = 0.f;
    #pragma unroll
    for (int ch = 0; ch < CH; ++ch) {
        float n[9];
        #pragma unroll
        for (int dy = 0; dy < 3; ++dy)
            #pragma unroll
            for (int dx = 0; dx < 3; ++dx)
                n[dy * 3 + dx] = sbuf[ch][ly + dy][lx + dx];
        float qc = q[ch];
        const float4* wp = (const float4*)&wcp[ch * 108];
        #pragma unroll
        for (int ka = 0; ka < 9; ++ka) {
            float4 a4 = wp[ka * 3 + 0];
            float4 b4 = wp[ka * 3 + 1];
            float4 c4 = wp[ka * 3 + 2];
            float kv = n[ka] + c4.y;
            kv += n[0]*a4.x + n[1]*a4.y + n[2]*a4.z + n[3]*a4.w;
            kv += n[4]*b4.x + n[5]*b4.y + n[6]*b4.z + n[7]*b4.w;
            kv += n[8]*c4.x;
            logits[ka] += qc * kv;
        }
    }

    // ---- softmax over 9
    float m = logits[0];
    #pragma unroll
    for (int ka = 1; ka < 9; ++ka) m = fmaxf(m, logits[ka]);
    float att[9];
    float s = 0.f;
    #pragma unroll
    for (int ka = 0; ka < 9; ++ka) { att[ka] = __expf(logits[ka] - m); s += att[ka]; }
    float inv = 1.f / s;
    #pragma unroll
    for (int ka = 0; ka < 9; ++ka) att[ka] *= inv;

    // ---- stream v halo into the same buffer
    __syncthreads();
    for (int idx = tid; idx < 8 * HALO; idx += 448) {
        int ch  = idx / HALO;
        int rem = idx - ch * HALO;
        int row = rem / (WW + 2);
        int col = rem - row * (WW + 2);
        int gy = ty0 + row - 1;
        int gx = col - 1;
        float val = 0.f;
        if (gy >= 0 && gy < HH && gx >= 0 && gx < WW)
            val = fb[(16 + ch) * POS + gy * WW + gx];
        (&sbuf[0][0][0])[idx] = val;
    }
    __syncthreads();

    // ---- V pass
    float outv[CH];
    #pragma unroll
    for (int ch = 0; ch < CH; ++ch) {
        float n[9];
        #pragma unroll
        for (int dy = 0; dy < 3; ++dy)
            #pragma unroll
            for (int dx = 0; dx < 3; ++dx)
                n[dy * 3 + dx] = sbuf[ch][ly + dy][lx + dx];
        const float4* wp = (const float4*)&wcp[ch * 108];
        float o = 0.f;
        #pragma unroll
        for (int ka = 0; ka < 9; ++ka) {
            float4 a4 = wp[ka * 3 + 0];
            float4 b4 = wp[ka * 3 + 1];
            float4 c4 = wp[ka * 3 + 2];
            float vv = n[ka] + c4.z;
            vv += n[0]*a4.x + n[1]*a4.y + n[2]*a4.z + n[3]*a4.w;
            vv += n[4]*b4.x + n[5]*b4.y + n[6]*b4.z + n[7]*b4.w;
            vv += n[8]*c4.x;
            o += att[ka] * vv;
        }
        outv[ch] = o;
    }

    float* ap = aout + ((size_t)b * OC + h * CH) * POS + pos;
    #pragma unroll
    for (int ch = 0; ch < CH; ++ch) ap[ch * POS] = outv[ch];
}

// ---------------------------------------------------------------------------
// Kernel C: out = a @ proj_w^T + proj_b via bf16 MFMA, fp32 NCHW out.
// Mtile=64, Ntile=128, K=64. grid (49, 2, 16)
// ---------------------------------------------------------------------------
__global__ __launch_bounds__(256) void proj_mfma(const float* __restrict__ a,
                                                 const float* __restrict__ w,
                                                 const float* __restrict__ bias,
                                                 float* __restrict__ out) {
    __shared__ __align__(16) unsigned short wa[64 * 72];    // [m][k] stride 72
    __shared__ __align__(16) unsigned short wb[128 * 72];   // [n][k]
    const int tid = threadIdx.x;
    const int p0  = blockIdx.x * 64;
    const int o0  = blockIdx.y * 128;
    const int b   = blockIdx.z;

    // stage A with transpose: a[b][ch][p0+p] fp32 -> wa[p][ch] bf16
    {
        const int c2 = (tid & 31) * 2;       // ch pair 0..62
        const int p8 = (tid >> 5) * 8;       // 8 pos per thread
        const float* ab = a + (size_t)b * OC * POS + p0;
        const float4 r0a = *(const float4*)(ab + (size_t)c2 * POS + p8);
        const float4 r0b = *(const float4*)(ab + (size_t)c2 * POS + p8 + 4);
        const float4 r1a = *(const float4*)(ab + (size_t)(c2 + 1) * POS + p8);
        const float4 r1b = *(const float4*)(ab + (size_t)(c2 + 1) * POS + p8 + 4);
        *(unsigned int*)&wa[(p8 + 0) * 72 + c2] = pk(r0a.x, r1a.x);
        *(unsigned int*)&wa[(p8 + 1) * 72 + c2] = pk(r0a.y, r1a.y);
        *(unsigned int*)&wa[(p8 + 2) * 72 + c2] = pk(r0a.z, r1a.z);
        *(unsigned int*)&wa[(p8 + 3) * 72 + c2] = pk(r0a.w, r1a.w);
        *(unsigned int*)&wa[(p8 + 4) * 72 + c2] = pk(r0b.x, r1b.x);
        *(unsigned int*)&wa[(p8 + 5) * 72 + c2] = pk(r0b.y, r1b.y);
        *(unsigned int*)&wa[(p8 + 6) * 72 + c2] = pk(r0b.z, r1b.z);
        *(unsigned int*)&wa[(p8 + 7) * 72 + c2] = pk(r0b.w, r1b.w);
    }
    // stage B: proj_w[o0+o][ch] 128x64 fp32 -> bf16
    for (int idx = tid; idx < 2048; idx += 256) {
        int o = idx >> 4, c4 = (idx & 15) << 2;
        const float4 t = *(const float4*)(w + (size_t)(o0 + o) * 64 + c4);
        *(unsigned int*)&wb[o * 72 + c4]     = pk(t.x, t.y);
        *(unsigned int*)&wb[o * 72 + c4 + 2] = pk(t.z, t.w);
    }
    __syncthreads();

    const int lane = tid & 63;
    const int wid  = tid >> 6;
    const int m0   = wid * 16;
    const int ml   = lane & 15;
    const int kg   = lane >> 4;

    f32x4 acc[8];
    #pragma unroll
    for (int u = 0; u < 8; ++u) acc[u] = (f32x4){0.f, 0.f, 0.f, 0.f};

    #pragma unroll
    for (int s = 0; s < 2; ++s) {
        bf16x8 af = *(const bf16x8*)&wa[(m0 + ml) * 72 + s * 32 + kg * 8];
        #pragma unroll
        for (int u = 0; u < 8; ++u) {
            bf16x8 bf = *(const bf16x8*)&wb[(u * 16 + ml) * 72 + s * 32 + kg * 8];
            acc[u] = __builtin_amdgcn_mfma_f32_16x16x32_bf16(af, bf, acc[u], 0, 0, 0);
        }
    }

    #pragma unroll
    for (int u = 0; u < 8; ++u) {
        int o = o0 + u * 16 + ml;
        float bj = bias[o];
        float4 st = { acc[u][0] + bj, acc[u][1] + bj, acc[u][2] + bj, acc[u][3] + bj };
        *(float4*)(out + ((size_t)b * 256 + o) * POS + p0 + m0 + kg * 4) = st;
    }
}

// ---------------------------------------------------------------------------
extern "C" void kernel_launch(void* const* d_in, const int* in_sizes, int n_in,
                              void* d_out, int out_size, void* d_ws, size_t ws_size,
                              hipStream_t stream) {
    const float* x      = (const float*)d_in[0];
    const float* qkv_w  = (const float*)d_in[1];
    const float* qkv_b  = (const float*)d_in[2];
    const float* dc_b   = (const float*)d_in[3];
    const float* dc1_w  = (const float*)d_in[4];
    const float* dc1_b  = (const float*)d_in[5];
    const float* rpb    = (const float*)d_in[6];
    const float* proj_w = (const float*)d_in[7];
    const float* proj_b = (const float*)d_in[8];
    float* out = (float*)d_out;

    // ws: f fp32 38.5 MB + a fp32 12.8 MB
    float* f = (float*)d_ws;
    float* a = f + (size_t)BATCH * QKVC * POS;

    qkv_mfma<<<dim3(49, 2, BATCH), 256, 0, stream>>>(x, qkv_w, qkv_b, f);
    attn_kernel<<<dim3(7, NH, BATCH), 448, 0, stream>>>(f, dc_b, dc1_w, dc1_b, rpb, a);
    proj_mfma<<<dim3(49, 2, BATCH), 256, 0, stream>>>(a, proj_w, proj_b, out);
}

// Round 7
// 223.037 us; speedup vs baseline: 3.4660x; 3.4660x over previous
//
#include <hip/hip_runtime.h>
#include <hip/hip_bf16.h>

#define BATCH 16
#define NH    8
#define CH    8
#define HH    56
#define WW    56
#define POS   3136          // 56*56 = 49*64
#define QKVC  192
#define OC    64
#define SCALE 0.17677669529663687f   // 32^-0.5

typedef __attribute__((ext_vector_type(8))) short bf16x8;   // 8 bf16 = 4 VGPRs
typedef __attribute__((ext_vector_type(4))) float f32x4;

__device__ __forceinline__ unsigned short f2b(float f) {
    __hip_bfloat16 h = __float2bfloat16(f);
    union { __hip_bfloat16 h; unsigned short u; } c; c.h = h; return c.u;
}
__device__ __forceinline__ unsigned int pk(float lo, float hi) {
    return (unsigned int)f2b(lo) | ((unsigned int)f2b(hi) << 16);
}

// ---------------------------------------------------------------------------
// Kernel A: qkv = x @ qkv_w^T + qkv_b via bf16 MFMA, f[b][o][pos] fp32.
// Mtile=64, Ntile=96, FULL K=256 staged once -> 48 MFMAs/wave, no inner
// barriers. LDS 84.5 KB. grid (49, 2, 16), 256 thr.
// ---------------------------------------------------------------------------
__global__ __launch_bounds__(256) void qkv_mfma(const float* __restrict__ x,
                                                const float* __restrict__ w,
                                                const float* __restrict__ bias,
                                                float* __restrict__ f) {
    __shared__ __align__(16) unsigned short wa[64 * 264];   // [m=pos][k=c] stride 264
    __shared__ __align__(16) unsigned short wb[96 * 264];   // [n=o][k=c]
    const int tid = threadIdx.x;
    const int p0  = blockIdx.x * 64;
    const int o0  = blockIdx.y * 96;
    const int b   = blockIdx.z;

    // stage A: transpose x[c][p0..p0+63] fp32 -> wa[p][c] bf16, all 256 c.
    {
        const float* xb = x + (size_t)b * 256 * POS + p0;
        const int cl = (tid & 15) * 2;       // c-pair base
        const int p4 = (tid >> 4) * 4;       // 4 pos per thread
        #pragma unroll
        for (int it = 0; it < 8; ++it) {
            const int c2 = cl + it * 32;
            const float4 r0 = *(const float4*)(xb + (size_t)c2 * POS + p4);
            const float4 r1 = *(const float4*)(xb + (size_t)(c2 + 1) * POS + p4);
            *(unsigned int*)&wa[(p4 + 0) * 264 + c2] = pk(r0.x, r1.x);
            *(unsigned int*)&wa[(p4 + 1) * 264 + c2] = pk(r0.y, r1.y);
            *(unsigned int*)&wa[(p4 + 2) * 264 + c2] = pk(r0.z, r1.z);
            *(unsigned int*)&wa[(p4 + 3) * 264 + c2] = pk(r0.w, r1.w);
        }
    }
    // stage B: w[o0+o][c] 96x256 fp32 -> bf16
    for (int idx = tid; idx < 96 * 64; idx += 256) {
        int o  = idx >> 6;
        int c4 = (idx & 63) << 2;
        const float4 t = *(const float4*)(w + (size_t)(o0 + o) * 256 + c4);
        *(unsigned int*)&wb[o * 264 + c4]     = pk(t.x, t.y);
        *(unsigned int*)&wb[o * 264 + c4 + 2] = pk(t.z, t.w);
    }
    __syncthreads();

    const int lane = tid & 63;
    const int wid  = tid >> 6;          // wave 0..3
    const int m0   = wid * 16;
    const int ml   = lane & 15;
    const int kg   = lane >> 4;         // 0..3

    f32x4 acc[6];
    #pragma unroll
    for (int u = 0; u < 6; ++u) acc[u] = (f32x4){0.f, 0.f, 0.f, 0.f};

    #pragma unroll
    for (int ks = 0; ks < 8; ++ks) {
        const int c0 = ks * 32;
        bf16x8 af = *(const bf16x8*)&wa[(m0 + ml) * 264 + c0 + kg * 8];
        #pragma unroll
        for (int u = 0; u < 6; ++u) {
            bf16x8 bf = *(const bf16x8*)&wb[(u * 16 + ml) * 264 + c0 + kg * 8];
            acc[u] = __builtin_amdgcn_mfma_f32_16x16x32_bf16(af, bf, acc[u], 0, 0, 0);
        }
    }

    // epilogue: D row=(kg*4+r)=pos offset, col=ml=o offset
    #pragma unroll
    for (int u = 0; u < 6; ++u) {
        int o = o0 + u * 16 + ml;
        float bj = bias[o];
        float4 st = { acc[u][0] + bj, acc[u][1] + bj, acc[u][2] + bj, acc[u][3] + bj };
        *(float4*)(f + ((size_t)b * QKVC + o) * POS + p0 + m0 + kg * 4) = st;
    }
}

// ---------------------------------------------------------------------------
// Kernel B: slide attention (fp32), R5-proven body: dual K/V LDS buffers,
// plain launch bounds (VGPR 108, no spills), coalesced fp32 store.
// grid (7, 8, 16), 448 thr.
// ---------------------------------------------------------------------------
#define TBH 8
__global__ __launch_bounds__(448) void attn_kernel(const float* __restrict__ f,
                                                   const float* __restrict__ dc_b,
                                                   const float* __restrict__ dc1_w,
                                                   const float* __restrict__ dc1_b,
                                                   const float* __restrict__ rpb,
                                                   float* __restrict__ aout) {
    __shared__ float kbuf[CH][TBH + 2][WW + 2];
    __shared__ float vbuf[CH][TBH + 2][WW + 2];
    __shared__ float wcp[CH * 9 * 12];

    const int tid = threadIdx.x;
    const int ty0 = blockIdx.x * TBH;
    const int h   = blockIdx.y;
    const int b   = blockIdx.z;
    const float* fb = f + ((size_t)b * QKVC + h * 24) * POS;

    const int HALO = (TBH + 2) * (WW + 2);   // 580
    for (int idx = tid; idx < 16 * HALO; idx += 448) {
        int c16 = idx / HALO;
        int rem = idx - c16 * HALO;
        int row = rem / (WW + 2);
        int col = rem - row * (WW + 2);
        int gy = ty0 + row - 1;
        int gx = col - 1;
        float val = 0.f;
        if (gy >= 0 && gy < HH && gx >= 0 && gx < WW) {
            int ch = c16 & 7;
            int o  = (c16 < 8) ? (8 + ch) : (16 + ch);
            val = fb[o * POS + gy * WW + gx];
        }
        float* dst = (c16 < 8) ? &kbuf[c16 & 7][0][0] : &vbuf[c16 & 7][0][0];
        dst[rem] = val;
    }
    for (int idx = tid; idx < 72; idx += 448) {
        int base = idx * 12;
        #pragma unroll
        for (int j = 0; j < 9; ++j) wcp[base + j] = dc1_w[idx * 9 + j];
        float db = dc_b[idx] + dc1_b[idx];
        int ka = idx % 9;
        wcp[base + 9]  = db + rpb[h * 9 + ka];
        wcp[base + 10] = db;
        wcp[base + 11] = 0.f;
    }
    __syncthreads();

    const int ly  = tid / WW;
    const int lx  = tid - ly * WW;
    const int pos = (ty0 + ly) * WW + lx;

    float q[CH];
    #pragma unroll
    for (int ch = 0; ch < CH; ++ch) q[ch] = fb[ch * POS + pos] * SCALE;

    float logits[9];
    #pragma unroll
    for (int ka = 0; ka < 9; ++ka) logits[ka] = 0.f;
    #pragma unroll
    for (int ch = 0; ch < CH; ++ch) {
        float n[9];
        #pragma unroll
        for (int dy = 0; dy < 3; ++dy)
            #pragma unroll
            for (int dx = 0; dx < 3; ++dx)
                n[dy * 3 + dx] = kbuf[ch][ly + dy][lx + dx];
        float qc = q[ch];
        const float4* wp = (const float4*)&wcp[ch * 108];
        #pragma unroll
        for (int ka = 0; ka < 9; ++ka) {
            float4 a4 = wp[ka * 3 + 0];
            float4 b4 = wp[ka * 3 + 1];
            float4 c4 = wp[ka * 3 + 2];
            float kv = n[ka] + c4.y;
            kv += n[0]*a4.x + n[1]*a4.y + n[2]*a4.z + n[3]*a4.w;
            kv += n[4]*b4.x + n[5]*b4.y + n[6]*b4.z + n[7]*b4.w;
            kv += n[8]*c4.x;
            logits[ka] += qc * kv;
        }
    }

    float m = logits[0];
    #pragma unroll
    for (int ka = 1; ka < 9; ++ka) m = fmaxf(m, logits[ka]);
    float att[9];
    float s = 0.f;
    #pragma unroll
    for (int ka = 0; ka < 9; ++ka) { att[ka] = __expf(logits[ka] - m); s += att[ka]; }
    float inv = 1.f / s;
    #pragma unroll
    for (int ka = 0; ka < 9; ++ka) att[ka] *= inv;

    float outv[CH];
    #pragma unroll
    for (int ch = 0; ch < CH; ++ch) {
        float n[9];
        #pragma unroll
        for (int dy = 0; dy < 3; ++dy)
            #pragma unroll
            for (int dx = 0; dx < 3; ++dx)
                n[dy * 3 + dx] = vbuf[ch][ly + dy][lx + dx];
        const float4* wp = (const float4*)&wcp[ch * 108];
        float o = 0.f;
        #pragma unroll
        for (int ka = 0; ka < 9; ++ka) {
            float4 a4 = wp[ka * 3 + 0];
            float4 b4 = wp[ka * 3 + 1];
            float4 c4 = wp[ka * 3 + 2];
            float vv = n[ka] + c4.z;
            vv += n[0]*a4.x + n[1]*a4.y + n[2]*a4.z + n[3]*a4.w;
            vv += n[4]*b4.x + n[5]*b4.y + n[6]*b4.z + n[7]*b4.w;
            vv += n[8]*c4.x;
            o += att[ka] * vv;
        }
        outv[ch] = o;
    }

    // coalesced fp32 store: aout[b][h*8+ch][pos], single-writer full lines
    float* ap = aout + ((size_t)b * OC + h * CH) * POS + pos;
    #pragma unroll
    for (int ch = 0; ch < CH; ++ch) ap[ch * POS] = outv[ch];
}

// ---------------------------------------------------------------------------
// Kernel C: out = a @ proj_w^T + proj_b via bf16 MFMA, fp32 NCHW out.
// Mtile=64, Ntile=128, K=64. grid (49, 2, 16)
// ---------------------------------------------------------------------------
__global__ __launch_bounds__(256) void proj_mfma(const float* __restrict__ a,
                                                 const float* __restrict__ w,
                                                 const float* __restrict__ bias,
                                                 float* __restrict__ out) {
    __shared__ __align__(16) unsigned short wa[64 * 72];    // [m][k] stride 72
    __shared__ __align__(16) unsigned short wb[128 * 72];   // [n][k]
    const int tid = threadIdx.x;
    const int p0  = blockIdx.x * 64;
    const int o0  = blockIdx.y * 128;
    const int b   = blockIdx.z;

    // stage A with transpose: a[b][ch][p0+p] fp32 -> wa[p][ch] bf16
    {
        const int c2 = (tid & 31) * 2;       // ch pair 0..62
        const int p8 = (tid >> 5) * 8;       // 8 pos per thread
        const float* ab = a + (size_t)b * OC * POS + p0;
        const float4 r0a = *(const float4*)(ab + (size_t)c2 * POS + p8);
        const float4 r0b = *(const float4*)(ab + (size_t)c2 * POS + p8 + 4);
        const float4 r1a = *(const float4*)(ab + (size_t)(c2 + 1) * POS + p8);
        const float4 r1b = *(const float4*)(ab + (size_t)(c2 + 1) * POS + p8 + 4);
        *(unsigned int*)&wa[(p8 + 0) * 72 + c2] = pk(r0a.x, r1a.x);
        *(unsigned int*)&wa[(p8 + 1) * 72 + c2] = pk(r0a.y, r1a.y);
        *(unsigned int*)&wa[(p8 + 2) * 72 + c2] = pk(r0a.z, r1a.z);
        *(unsigned int*)&wa[(p8 + 3) * 72 + c2] = pk(r0a.w, r1a.w);
        *(unsigned int*)&wa[(p8 + 4) * 72 + c2] = pk(r0b.x, r1b.x);
        *(unsigned int*)&wa[(p8 + 5) * 72 + c2] = pk(r0b.y, r1b.y);
        *(unsigned int*)&wa[(p8 + 6) * 72 + c2] = pk(r0b.z, r1b.z);
        *(unsigned int*)&wa[(p8 + 7) * 72 + c2] = pk(r0b.w, r1b.w);
    }
    // stage B: proj_w[o0+o][ch] 128x64 fp32 -> bf16
    for (int idx = tid; idx < 2048; idx += 256) {
        int o = idx >> 4, c4 = (idx & 15) << 2;
        const float4 t = *(const float4*)(w + (size_t)(o0 + o) * 64 + c4);
        *(unsigned int*)&wb[o * 72 + c4]     = pk(t.x, t.y);
        *(unsigned int*)&wb[o * 72 + c4 + 2] = pk(t.z, t.w);
    }
    __syncthreads();

    const int lane = tid & 63;
    const int wid  = tid >> 6;
    const int m0   = wid * 16;
    const int ml   = lane & 15;
    const int kg   = lane >> 4;

    f32x4 acc[8];
    #pragma unroll
    for (int u = 0; u < 8; ++u) acc[u] = (f32x4){0.f, 0.f, 0.f, 0.f};

    #pragma unroll
    for (int s = 0; s < 2; ++s) {
        bf16x8 af = *(const bf16x8*)&wa[(m0 + ml) * 72 + s * 32 + kg * 8];
        #pragma unroll
        for (int u = 0; u < 8; ++u) {
            bf16x8 bf = *(const bf16x8*)&wb[(u * 16 + ml) * 72 + s * 32 + kg * 8];
            acc[u] = __builtin_amdgcn_mfma_f32_16x16x32_bf16(af, bf, acc[u], 0, 0, 0);
        }
    }

    #pragma unroll
    for (int u = 0; u < 8; ++u) {
        int o = o0 + u * 16 + ml;
        float bj = bias[o];
        float4 st = { acc[u][0] + bj, acc[u][1] + bj, acc[u][2] + bj, acc[u][3] + bj };
        *(float4*)(out + ((size_t)b * 256 + o) * POS + p0 + m0 + kg * 4) = st;
    }
}

// ---------------------------------------------------------------------------
extern "C" void kernel_launch(void* const* d_in, const int* in_sizes, int n_in,
                              void* d_out, int out_size, void* d_ws, size_t ws_size,
                              hipStream_t stream) {
    const float* x      = (const float*)d_in[0];
    const float* qkv_w  = (const float*)d_in[1];
    const float* qkv_b  = (const float*)d_in[2];
    const float* dc_b   = (const float*)d_in[3];
    const float* dc1_w  = (const float*)d_in[4];
    const float* dc1_b  = (const float*)d_in[5];
    const float* rpb    = (const float*)d_in[6];
    const float* proj_w = (const float*)d_in[7];
    const float* proj_b = (const float*)d_in[8];
    float* out = (float*)d_out;

    // ws: f fp32 38.5 MB + a fp32 12.8 MB
    float* f = (float*)d_ws;
    float* a = f + (size_t)BATCH * QKVC * POS;

    qkv_mfma<<<dim3(49, 2, BATCH), 256, 0, stream>>>(x, qkv_w, qkv_b, f);
    attn_kernel<<<dim3(7, NH, BATCH), 448, 0, stream>>>(f, dc_b, dc1_w, dc1_b, rpb, a);
    proj_mfma<<<dim3(49, 2, BATCH), 256, 0, stream>>>(a, proj_w, proj_b, out);
}

// Round 8
// 206.371 us; speedup vs baseline: 3.7459x; 1.0808x over previous
//
#include <hip/hip_runtime.h>
#include <hip/hip_bf16.h>

#define BATCH 16
#define NH    8
#define CH    8
#define HH    56
#define WW    56
#define POS   3136          // 56*56 = 49*64
#define QKVC  192
#define OC    64
#define SCALE 0.17677669529663687f   // 32^-0.5

typedef unsigned short ushort_t;
typedef __attribute__((ext_vector_type(8))) short bf16x8;   // 8 bf16 = 4 VGPRs
typedef __attribute__((ext_vector_type(4))) float f32x4;

__device__ __forceinline__ unsigned short f2b(float f) {
    __hip_bfloat16 h = __float2bfloat16(f);
    union { __hip_bfloat16 h; unsigned short u; } c; c.h = h; return c.u;
}
__device__ __forceinline__ unsigned int pk(float lo, float hi) {
    return (unsigned int)f2b(lo) | ((unsigned int)f2b(hi) << 16);
}
__device__ __forceinline__ float bu2f(ushort_t u) {
    union { unsigned int v; float f; } c; c.v = ((unsigned int)u) << 16; return c.f;
}
// async 16B global->LDS (lane-linear dest within wave)
__device__ __forceinline__ void gll16(const ushort_t* g, ushort_t* l) {
    __builtin_amdgcn_global_load_lds((const __attribute__((address_space(1))) void*)g,
                                     (__attribute__((address_space(3))) void*)l, 16, 0, 0);
}

// ---------------------------------------------------------------------------
// prep_x: x[b][c][pos] fp32 -> xT[b][pos][c] bf16 (canonical, no swizzle).
// 64c x 64p tile via LDS. grid (49, 4, 16), 256 thr.
// ---------------------------------------------------------------------------
__global__ __launch_bounds__(256) void prep_x(const float* __restrict__ x,
                                              ushort_t* __restrict__ xT) {
    __shared__ float ld[64][65];
    const int tid = threadIdx.x;
    const int p0 = blockIdx.x * 64, c0 = blockIdx.y * 64, b = blockIdx.z;
    const float* xb = x + ((size_t)b * 256 + c0) * POS + p0;
    #pragma unroll
    for (int it = 0; it < 4; ++it) {
        int idx = it * 256 + tid;
        int c = idx >> 4, pc = (idx & 15) << 2;
        float4 v = *(const float4*)(xb + (size_t)c * POS + pc);
        ld[c][pc] = v.x; ld[c][pc+1] = v.y; ld[c][pc+2] = v.z; ld[c][pc+3] = v.w;
    }
    __syncthreads();
    ushort_t* xo = xT + ((size_t)(b * POS + p0)) * 256 + c0;
    #pragma unroll
    for (int it = 0; it < 2; ++it) {
        int idx = it * 256 + tid;
        int p = idx >> 3, q = (idx & 7) * 8;
        uint4 st = { pk(ld[q][p],   ld[q+1][p]), pk(ld[q+2][p], ld[q+3][p]),
                     pk(ld[q+4][p], ld[q+5][p]), pk(ld[q+6][p], ld[q+7][p]) };
        *(uint4*)(xo + (size_t)p * 256 + q) = st;
    }
}

// ---------------------------------------------------------------------------
// prep_w: qkv_w (192x256) + proj_w (256x64) fp32 -> bf16. grid(64), 256 thr.
// ---------------------------------------------------------------------------
__global__ __launch_bounds__(256) void prep_w(const float* __restrict__ wq,
                                              const float* __restrict__ wp,
                                              ushort_t* __restrict__ wq16,
                                              ushort_t* __restrict__ wp16) {
    int idx = blockIdx.x * 256 + threadIdx.x;   // 16384 float4 units
    const float* src; ushort_t* dst; int off;
    if (idx < 12288) { src = wq; dst = wq16; off = idx * 4; }
    else             { src = wp; dst = wp16; off = (idx - 12288) * 4; }
    float4 v = *(const float4*)(src + off);
    uint2 st = { pk(v.x, v.y), pk(v.z, v.w) };
    *(uint2*)(dst + off) = st;
}

// ---------------------------------------------------------------------------
// qkv: f = x @ qkv_w^T + b via bf16 MFMA, f bf16 [b][o][pos].
// Mtile=64, Ntile=96, full K=256. Staging 100% global_load_lds w/ XOR swizzle
// (rows 512B bank-aligned; chunk q stored at q^(row&7)). LDS 80KB = 2 blk/CU.
// grid (49, 2, 16), 256 thr.
// ---------------------------------------------------------------------------
__global__ __launch_bounds__(256) void qkv_mfma(const ushort_t* __restrict__ xT,
                                                const ushort_t* __restrict__ wq16,
                                                const float* __restrict__ bias,
                                                ushort_t* __restrict__ f16) {
    __shared__ __align__(16) ushort_t wa[64 * 256];
    __shared__ __align__(16) ushort_t wb[96 * 256];
    const int tid = threadIdx.x;
    const int p0 = blockIdx.x * 64, o0 = blockIdx.y * 96, b = blockIdx.z;

    const ushort_t* xb = xT + ((size_t)(b * POS + p0)) * 256;
    #pragma unroll
    for (int it = 0; it < 8; ++it) {        // A: 64 rows x 32 chunks
        int idx = it * 256 + tid;
        int p = idx >> 5, q = idx & 31, qs = q ^ (p & 7);
        gll16(xb + (size_t)p * 256 + qs * 8, &wa[idx * 8]);
    }
    #pragma unroll
    for (int it = 0; it < 12; ++it) {       // B: 96 rows x 32 chunks
        int idx = it * 256 + tid;
        int n = idx >> 5, q = idx & 31, qs = q ^ (n & 7);
        gll16(wq16 + (size_t)(o0 + n) * 256 + qs * 8, &wb[idx * 8]);
    }
    __syncthreads();

    const int lane = tid & 63;
    const int wid  = tid >> 6;
    const int m0   = wid * 16;
    const int ml   = lane & 15;
    const int kg   = lane >> 4;

    f32x4 acc[6];
    #pragma unroll
    for (int u = 0; u < 6; ++u) acc[u] = (f32x4){0.f, 0.f, 0.f, 0.f};

    #pragma unroll
    for (int ks = 0; ks < 8; ++ks) {
        const int pj = ((ks * 4 + kg) ^ (ml & 7)) * 8;   // swizzled chunk (m&7==n&7==ml&7)
        bf16x8 af = *(const bf16x8*)&wa[(m0 + ml) * 256 + pj];
        #pragma unroll
        for (int u = 0; u < 6; ++u) {
            bf16x8 bf = *(const bf16x8*)&wb[(u * 16 + ml) * 256 + pj];
            acc[u] = __builtin_amdgcn_mfma_f32_16x16x32_bf16(af, bf, acc[u], 0, 0, 0);
        }
    }

    #pragma unroll
    for (int u = 0; u < 6; ++u) {
        int o = o0 + u * 16 + ml;
        float bj = bias[o];
        uint2 st = { pk(acc[u][0] + bj, acc[u][1] + bj),
                     pk(acc[u][2] + bj, acc[u][3] + bj) };
        *(uint2*)(f16 + ((size_t)b * QKVC + o) * POS + p0 + m0 + kg * 4) = st;
    }
}

// ---------------------------------------------------------------------------
// attn: R7-proven body, f now bf16. grid (7, 8, 16), 448 thr.
// ---------------------------------------------------------------------------
#define TBH 8
__global__ __launch_bounds__(448) void attn_kernel(const ushort_t* __restrict__ f16,
                                                   const float* __restrict__ dc_b,
                                                   const float* __restrict__ dc1_w,
                                                   const float* __restrict__ dc1_b,
                                                   const float* __restrict__ rpb,
                                                   float* __restrict__ aout) {
    __shared__ float kbuf[CH][TBH + 2][WW + 2];
    __shared__ float vbuf[CH][TBH + 2][WW + 2];
    __shared__ float wcp[CH * 9 * 12];

    const int tid = threadIdx.x;
    const int ty0 = blockIdx.x * TBH;
    const int h   = blockIdx.y;
    const int b   = blockIdx.z;
    const ushort_t* fb = f16 + ((size_t)b * QKVC + h * 24) * POS;

    const int HALO = (TBH + 2) * (WW + 2);   // 580
    for (int idx = tid; idx < 16 * HALO; idx += 448) {
        int c16 = idx / HALO;
        int rem = idx - c16 * HALO;
        int row = rem / (WW + 2);
        int col = rem - row * (WW + 2);
        int gy = ty0 + row - 1;
        int gx = col - 1;
        float val = 0.f;
        if (gy >= 0 && gy < HH && gx >= 0 && gx < WW) {
            int ch = c16 & 7;
            int o  = (c16 < 8) ? (8 + ch) : (16 + ch);
            val = bu2f(fb[o * POS + gy * WW + gx]);
        }
        float* dst = (c16 < 8) ? &kbuf[c16 & 7][0][0] : &vbuf[c16 & 7][0][0];
        dst[rem] = val;
    }
    for (int idx = tid; idx < 72; idx += 448) {
        int base = idx * 12;
        #pragma unroll
        for (int j = 0; j < 9; ++j) wcp[base + j] = dc1_w[idx * 9 + j];
        float db = dc_b[idx] + dc1_b[idx];
        int ka = idx % 9;
        wcp[base + 9]  = db + rpb[h * 9 + ka];
        wcp[base + 10] = db;
        wcp[base + 11] = 0.f;
    }
    __syncthreads();

    const int ly  = tid / WW;
    const int lx  = tid - ly * WW;
    const int pos = (ty0 + ly) * WW + lx;

    float q[CH];
    #pragma unroll
    for (int ch = 0; ch < CH; ++ch) q[ch] = bu2f(fb[ch * POS + pos]) * SCALE;

    float logits[9];
    #pragma unroll
    for (int ka = 0; ka < 9; ++ka) logits[ka] = 0.f;
    #pragma unroll
    for (int ch = 0; ch < CH; ++ch) {
        float n[9];
        #pragma unroll
        for (int dy = 0; dy < 3; ++dy)
            #pragma unroll
            for (int dx = 0; dx < 3; ++dx)
                n[dy * 3 + dx] = kbuf[ch][ly + dy][lx + dx];
        float qc = q[ch];
        const float4* wp = (const float4*)&wcp[ch * 108];
        #pragma unroll
        for (int ka = 0; ka < 9; ++ka) {
            float4 a4 = wp[ka * 3 + 0];
            float4 b4 = wp[ka * 3 + 1];
            float4 c4 = wp[ka * 3 + 2];
            float kv = n[ka] + c4.y;
            kv += n[0]*a4.x + n[1]*a4.y + n[2]*a4.z + n[3]*a4.w;
            kv += n[4]*b4.x + n[5]*b4.y + n[6]*b4.z + n[7]*b4.w;
            kv += n[8]*c4.x;
            logits[ka] += qc * kv;
        }
    }

    float m = logits[0];
    #pragma unroll
    for (int ka = 1; ka < 9; ++ka) m = fmaxf(m, logits[ka]);
    float att[9];
    float s = 0.f;
    #pragma unroll
    for (int ka = 0; ka < 9; ++ka) { att[ka] = __expf(logits[ka] - m); s += att[ka]; }
    float inv = 1.f / s;
    #pragma unroll
    for (int ka = 0; ka < 9; ++ka) att[ka] *= inv;

    float outv[CH];
    #pragma unroll
    for (int ch = 0; ch < CH; ++ch) {
        float n[9];
        #pragma unroll
        for (int dy = 0; dy < 3; ++dy)
            #pragma unroll
            for (int dx = 0; dx < 3; ++dx)
                n[dy * 3 + dx] = vbuf[ch][ly + dy][lx + dx];
        const float4* wp = (const float4*)&wcp[ch * 108];
        float o = 0.f;
        #pragma unroll
        for (int ka = 0; ka < 9; ++ka) {
            float4 a4 = wp[ka * 3 + 0];
            float4 b4 = wp[ka * 3 + 1];
            float4 c4 = wp[ka * 3 + 2];
            float vv = n[ka] + c4.z;
            vv += n[0]*a4.x + n[1]*a4.y + n[2]*a4.z + n[3]*a4.w;
            vv += n[4]*b4.x + n[5]*b4.y + n[6]*b4.z + n[7]*b4.w;
            vv += n[8]*c4.x;
            o += att[ka] * vv;
        }
        outv[ch] = o;
    }

    float* ap = aout + ((size_t)b * OC + h * CH) * POS + pos;
    #pragma unroll
    for (int ch = 0; ch < CH; ++ch) ap[ch * POS] = outv[ch];
}

// ---------------------------------------------------------------------------
// proj: out = a @ proj_w^T + b. A: coalesced fp32 -> LDS -> bf16 transpose.
// B: global_load_lds of pre-converted wp16 (swizzled). Mtile=64, Ntile=128.
// LDS ~42KB = 3 blk/CU. grid (49, 2, 16), 256 thr.
// ---------------------------------------------------------------------------
__global__ __launch_bounds__(256) void proj_mfma(const float* __restrict__ a,
                                                 const ushort_t* __restrict__ wp16,
                                                 const float* __restrict__ bias,
                                                 float* __restrict__ out) {
    __shared__ float ld[64][65];
    __shared__ __align__(16) ushort_t wa[64 * 72];
    __shared__ __align__(16) ushort_t wb[128 * 64];
    const int tid = threadIdx.x;
    const int p0 = blockIdx.x * 64, o0 = blockIdx.y * 128, b = blockIdx.z;

    // B: async GLL (rows 128B = 8 chunks, swizzled)
    #pragma unroll
    for (int it = 0; it < 4; ++it) {
        int idx = it * 256 + tid;
        int n = idx >> 3, q = idx & 7, qs = q ^ (n & 7);
        gll16(wp16 + (size_t)(o0 + n) * 64 + qs * 8, &wb[idx * 8]);
    }
    // A: coalesced fp32 tile
    const float* ab = a + (size_t)b * OC * POS + p0;
    #pragma unroll
    for (int it = 0; it < 4; ++it) {
        int idx = it * 256 + tid;
        int c = idx >> 4, pc = (idx & 15) << 2;
        float4 v = *(const float4*)(ab + (size_t)c * POS + pc);
        ld[c][pc] = v.x; ld[c][pc+1] = v.y; ld[c][pc+2] = v.z; ld[c][pc+3] = v.w;
    }
    __syncthreads();
    // pack transpose: wa[p][ch] stride 72
    #pragma unroll
    for (int it = 0; it < 2; ++it) {
        int idx = it * 256 + tid;
        int p = idx >> 3, q = (idx & 7) * 8;
        uint4 st = { pk(ld[q][p],   ld[q+1][p]), pk(ld[q+2][p], ld[q+3][p]),
                     pk(ld[q+4][p], ld[q+5][p]), pk(ld[q+6][p], ld[q+7][p]) };
        *(uint4*)&wa[p * 72 + q] = st;
    }
    __syncthreads();

    const int lane = tid & 63;
    const int wid  = tid >> 6;
    const int m0   = wid * 16;
    const int ml   = lane & 15;
    const int kg   = lane >> 4;

    f32x4 acc[8];
    #pragma unroll
    for (int u = 0; u < 8; ++u) acc[u] = (f32x4){0.f, 0.f, 0.f, 0.f};

    #pragma unroll
    for (int s = 0; s < 2; ++s) {
        bf16x8 af = *(const bf16x8*)&wa[(m0 + ml) * 72 + s * 32 + kg * 8];
        const int pj = ((s * 4 + kg) ^ (ml & 7)) * 8;
        #pragma unroll
        for (int u = 0; u < 8; ++u) {
            bf16x8 bf = *(const bf16x8*)&wb[(u * 16 + ml) * 64 + pj];
            acc[u] = __builtin_amdgcn_mfma_f32_16x16x32_bf16(af, bf, acc[u], 0, 0, 0);
        }
    }

    #pragma unroll
    for (int u = 0; u < 8; ++u) {
        int o = o0 + u * 16 + ml;
        float bj = bias[o];
        float4 st = { acc[u][0] + bj, acc[u][1] + bj, acc[u][2] + bj, acc[u][3] + bj };
        *(float4*)(out + ((size_t)b * 256 + o) * POS + p0 + m0 + kg * 4) = st;
    }
}

// ---------------------------------------------------------------------------
extern "C" void kernel_launch(void* const* d_in, const int* in_sizes, int n_in,
                              void* d_out, int out_size, void* d_ws, size_t ws_size,
                              hipStream_t stream) {
    const float* x      = (const float*)d_in[0];
    const float* qkv_w  = (const float*)d_in[1];
    const float* qkv_b  = (const float*)d_in[2];
    const float* dc_b   = (const float*)d_in[3];
    const float* dc1_w  = (const float*)d_in[4];
    const float* dc1_b  = (const float*)d_in[5];
    const float* rpb    = (const float*)d_in[6];
    const float* proj_w = (const float*)d_in[7];
    const float* proj_b = (const float*)d_in[8];
    float* out = (float*)d_out;

    // ws layout (45.1 MB total):
    //   f16   bf16 16*192*3136 = 19.27 MB
    //   xT    bf16 16*3136*256 = 25.69 MB  (dead after qkv; 'a' aliases it)
    //   wq16  96 KB, wp16 32 KB
    ushort_t* f16  = (ushort_t*)d_ws;
    ushort_t* xT   = f16 + (size_t)BATCH * QKVC * POS;
    ushort_t* wq16 = xT + (size_t)BATCH * POS * 256;
    ushort_t* wp16 = wq16 + 192 * 256;
    float*    a    = (float*)xT;            // alias: xT dead before attn writes

    prep_x   <<<dim3(49, 4, BATCH), 256, 0, stream>>>(x, xT);
    prep_w   <<<dim3(64),           256, 0, stream>>>(qkv_w, proj_w, wq16, wp16);
    qkv_mfma <<<dim3(49, 2, BATCH), 256, 0, stream>>>(xT, wq16, qkv_b, f16);
    attn_kernel<<<dim3(7, NH, BATCH), 448, 0, stream>>>(f16, dc_b, dc1_w, dc1_b, rpb, a);
    proj_mfma<<<dim3(49, 2, BATCH), 256, 0, stream>>>(a, wp16, proj_b, out);
}